// Round 11
// baseline (530.780 us; speedup 1.0000x reference)
//
#include <hip/hip_runtime.h>
#include <hip/hip_cooperative_groups.h>
#include <math.h>

namespace cg = cooperative_groups;

#define N_NODES 20000
#define N_EDGES 320000
#define CH      256
#define FEAT    118
#define CAP     48    // in-degree cap; dst ~ Poisson(16), P(any>48) ~ 2e-7
#define GRID    512   // 2 blocks/CU co-resident (launch_bounds 256,2) -- safe margin

typedef float    f32x4 __attribute__((ext_vector_type(4)));
typedef short    s16x8 __attribute__((ext_vector_type(8)));
typedef _Float16 f16x4 __attribute__((ext_vector_type(4)));
typedef _Float16 f16x8 __attribute__((ext_vector_type(8)));
typedef unsigned short u16;

union Frag  { s16x8 v; u16 u[8]; };
union FragH { f16x8 v; _Float16 h[8]; };

__device__ __forceinline__ float gelu_exact(float x) {
    return 0.5f * x * (1.0f + erff(x * 0.70710678118654752f));
}
__device__ __forceinline__ u16 f2bf(float f) {
    unsigned u = __float_as_uint(f);
    u = (u + 0x7FFFu + ((u >> 16) & 1u)) >> 16;
    return (u16)u;
}
__device__ __forceinline__ float bf2f(u16 h) { return __uint_as_float(((unsigned)h) << 16); }

struct MegaArgs {
    const float* x; const int* ei;
    const float* We; const float* be; const float* W1; const float* b1; const float* W2; const float* b2;
    u16* xh; u16* xl;
    int* cnt; int* bins;
    _Float16* w2h; _Float16* w2l;
    u16* wch; u16* wcl;
    float* bc;
    _Float16* M;
    _Float16* aggf;
    float* out;
};

// ===========================================================================
// Cooperative mega-kernel: 4 phases, 3 grid.sync()s.
//  P1: zero cnt | pack_x | pack W2 | compose Wc=We@W1, bc
//  P2: fill_bins || gemm_main (M = gelu(x@Wc+bc))
//  P3: aggregate (2 nodes/wave, 8-deep gathers each -> 16 loads in flight)
//  P4: gemm_mean (out = mean_ch gelu(agg@W2+b2))
// Fragment layouts (verified):
//  A-frag [mt][ks][lane][8]: elem j = A[mt*16+(lane&15)][ks*32+(lane>>4)*8+j]
//  B-frag [nt][ks][lane][8]: elem j = B[ks*32+(lane>>4)*8+j][nt*16+(lane&15)]
//  C-frag: col=lane&15, row=(lane>>4)*4+r
// ===========================================================================
__global__ __launch_bounds__(256, 2) void mega(MegaArgs a) {
    cg::grid_group grid = cg::this_grid();
    const int blk = blockIdx.x, tid = threadIdx.x;
    const int wave = tid >> 6, lane = tid & 63;
    const int quad = lane >> 4, lm = lane & 15;
    __shared__ __align__(16) char shraw[16 * 132 * 4];   // 8448 B, reused per phase

    // ================= Phase 1 =================
    for (int g = blk * 256 + tid; g < N_NODES; g += GRID * 256)
        a.cnt[g] = 0;
    for (int vb = blk; vb < 1411; vb += GRID) {
        if (vb < 1250) {                  // ---- pack_x: one 16-row m-tile
            float (&xs)[16][132] = *reinterpret_cast<float (*)[16][132]>(shraw);
            {
                int r = tid >> 4, ci = tid & 15;
                const float* xrow = a.x + (size_t)(vb * 16 + r) * FEAT;
                #pragma unroll
                for (int it = 0; it < 8; it++) {
                    int col = ci + it * 16;
                    xs[r][col] = (col < FEAT) ? xrow[col] : 0.0f;
                }
            }
            __syncthreads();
            int ks = wave;
            int row = lane & 15, k0 = ks * 32 + (lane >> 4) * 8;
            Frag hi, lo;
            #pragma unroll
            for (int j = 0; j < 8; j++) {
                float v = xs[row][k0 + j];
                u16 h = f2bf(v);
                hi.u[j] = h; lo.u[j] = f2bf(v - bf2f(h));
            }
            size_t fid = (size_t)vb * 256 + tid;
            ((s16x8*)a.xh)[fid] = hi.v;
            ((s16x8*)a.xl)[fid] = lo.v;
            __syncthreads();
        } else if (vb < 1282) {           // ---- pack W2 -> fp16 wh + 4096*wl, KS=8
            int fid = (vb - 1250) * 256 + tid;
            int l = fid & 63, ks = (fid >> 6) & 7, nt = fid >> 9;
            int n = nt * 16 + (l & 15);
            int k0 = ks * 32 + (l >> 4) * 8;
            FragH hi, lo;
            #pragma unroll
            for (int j = 0; j < 8; j++) {
                float v = a.W2[(size_t)(k0 + j) * 256 + n];
                _Float16 h = (_Float16)v;
                hi.h[j] = h;
                lo.h[j] = (_Float16)((v - (float)h) * 4096.0f);
            }
            ((f16x8*)a.w2h)[fid] = hi.v;
            ((f16x8*)a.w2l)[fid] = lo.v;
        } else {                          // ---- compose Wc row f (f<128) or bc
            int f = vb - 1282;
            int n = tid;
            if (f < 128) {
                float acc = 0.0f;
                if (f < FEAT) {
                    const float* wr = a.We + (size_t)f * 256;
                    #pragma unroll 8
                    for (int c = 0; c < 256; c++) acc += wr[c] * a.W1[(size_t)c * 256 + n];
                }
                int nt = n >> 4, lm2 = n & 15, ks = f >> 5, q = (f >> 3) & 3, j = f & 7;
                size_t idx = (((size_t)nt * 4 + ks) * 64 + q * 16 + lm2) * 8 + j;
                u16 h = f2bf(acc);
                a.wch[idx] = h;
                a.wcl[idx] = f2bf(acc - bf2f(h));
            } else {
                float acc = a.b1[n];
                #pragma unroll 8
                for (int c = 0; c < 256; c++) acc += a.be[c] * a.W1[(size_t)c * 256 + n];
                a.bc[n] = acc;
            }
        }
    }
    __threadfence();
    grid.sync();

    // ================= Phase 2: fill_bins || gemm_main =================
    for (int vb = blk; vb < 2500; vb += GRID) {
        if (vb < 1250) {                  // ---- fill_bins
            int e = vb * 256 + tid;
            int s = a.ei[e];
            int d = a.ei[N_EDGES + e];
            int p = atomicAdd(&a.cnt[d], 1);
            if (p < CAP) a.bins[(size_t)d * CAP + p] = s;
        } else {                          // ---- gemm_main 16-row m-tile
            int mt = vb - 1250;
            _Float16 (&Ls)[16][256] = *reinterpret_cast<_Float16 (*)[16][256]>(shraw);
            const s16x8* Ah = (const s16x8*)a.xh; const s16x8* Al = (const s16x8*)a.xl;
            const s16x8* Bh = (const s16x8*)a.wch; const s16x8* Bl = (const s16x8*)a.wcl;
            const int nt0 = wave * 4;
            f32x4 acc[4] = {f32x4{0,0,0,0}, f32x4{0,0,0,0}, f32x4{0,0,0,0}, f32x4{0,0,0,0}};
            #pragma unroll
            for (int ks = 0; ks < 4; ks++) {
                s16x8 a_h = Ah[((size_t)mt * 4 + ks) * 64 + lane];
                s16x8 a_l = Al[((size_t)mt * 4 + ks) * 64 + lane];
                #pragma unroll
                for (int t = 0; t < 4; t++) {
                    s16x8 bh = Bh[((size_t)(nt0 + t) * 4 + ks) * 64 + lane];
                    s16x8 bl = Bl[((size_t)(nt0 + t) * 4 + ks) * 64 + lane];
                    acc[t] = __builtin_amdgcn_mfma_f32_16x16x32_bf16(a_h, bh, acc[t], 0, 0, 0);
                    acc[t] = __builtin_amdgcn_mfma_f32_16x16x32_bf16(a_l, bh, acc[t], 0, 0, 0);
                    acc[t] = __builtin_amdgcn_mfma_f32_16x16x32_bf16(a_h, bl, acc[t], 0, 0, 0);
                }
            }
            #pragma unroll
            for (int t = 0; t < 4; t++) {
                float bn = a.bc[(nt0 + t) * 16 + lm];
                #pragma unroll
                for (int r = 0; r < 4; r++)
                    Ls[quad * 4 + r][(nt0 + t) * 16 + lm] = (_Float16)gelu_exact(acc[t][r] + bn);
            }
            __syncthreads();
            s16x8* dst = (s16x8*)a.M + (size_t)mt * 512;
            const s16x8* src = (const s16x8*)&Ls[0][0];
            dst[tid]       = src[tid];
            dst[256 + tid] = src[256 + tid];
            __syncthreads();
        }
    }
    __threadfence();
    grid.sync();

    // ================= Phase 3: aggregate, 2 nodes per wave =================
    for (int nb = (blk * 4 + wave) * 2; nb < N_NODES; nb += GRID * 8) {
        int c0 = a.cnt[nb],     cc0 = min(c0, CAP);
        int c1 = a.cnt[nb + 1], cc1 = min(c1, CAP);
        int id0 = (lane < CAP) ? a.bins[(size_t)nb * CAP + lane] : 0;
        int id1 = (lane < CAP) ? a.bins[(size_t)(nb + 1) * CAP + lane] : 0;
        float s0[4] = {0.f,0.f,0.f,0.f}, s1[4] = {0.f,0.f,0.f,0.f};
        int mx = max(cc0, cc1);
        for (int j = 0; j < mx; j += 8) {
            f16x4 v0[8], v1[8];
            #pragma unroll
            for (int u = 0; u < 8; u++) {
                int e0 = __shfl(id0, min(j + u, cc0 - 1), 64);
                int e1 = __shfl(id1, min(j + u, cc1 - 1), 64);
                v0[u] = *(const f16x4*)(a.M + (size_t)e0 * CH + lane * 4);
                v1[u] = *(const f16x4*)(a.M + (size_t)e1 * CH + lane * 4);
            }
            #pragma unroll
            for (int u = 0; u < 8; u++) {
                if (j + u < cc0) {
                    s0[0] += (float)v0[u].x; s0[1] += (float)v0[u].y;
                    s0[2] += (float)v0[u].z; s0[3] += (float)v0[u].w;
                }
                if (j + u < cc1) {
                    s1[0] += (float)v1[u].x; s1[1] += (float)v1[u].y;
                    s1[2] += (float)v1[u].z; s1[3] += (float)v1[u].w;
                }
            }
        }
        // ch = lane*4+q -> packed-A (KS=8): ks=lane>>3, quad=(lane&7)>>1, j0=(lane&1)*4
        int ks = lane >> 3, q2 = (lane & 7) >> 1, j0 = (lane & 1) * 4;
        #pragma unroll
        for (int which = 0; which < 2; which++) {
            int node = nb + which;
            int c = which ? c1 : c0;
            float* s = which ? s1 : s0;
            float inv = 1.0f / (float)max(c, 1);
            f16x4 o;
            o.x = (_Float16)(s[0] * inv); o.y = (_Float16)(s[1] * inv);
            o.z = (_Float16)(s[2] * inv); o.w = (_Float16)(s[3] * inv);
            int mt = node >> 4, lmn = node & 15;
            size_t base = (((size_t)mt * 8 + ks) * 64 + q2 * 16 + lmn) * 8 + j0;
            *(f16x4*)(a.aggf + base) = o;
        }
    }
    __threadfence();
    grid.sync();

    // ================= Phase 4: gemm_mean (16-row jobs) =================
    for (int vb = blk; vb < 1250; vb += GRID) {
        float (&part)[4][16] = *reinterpret_cast<float (*)[4][16]>(shraw);
        const int mt = vb, nt0 = wave * 4;
        const f16x8* Af = (const f16x8*)a.aggf;
        const f16x8* Bh = (const f16x8*)a.w2h; const f16x8* Bl = (const f16x8*)a.w2l;
        f32x4 acch[4], accl[4];
        #pragma unroll
        for (int t = 0; t < 4; t++) {
            acch[t] = f32x4{0.f, 0.f, 0.f, 0.f};
            accl[t] = f32x4{0.f, 0.f, 0.f, 0.f};
        }
        #pragma unroll
        for (int ks = 0; ks < 8; ks++) {
            f16x8 a0 = Af[((size_t)mt * 8 + ks) * 64 + lane];
            #pragma unroll
            for (int t = 0; t < 4; t++) {
                f16x8 bh = Bh[((size_t)(nt0 + t) * 8 + ks) * 64 + lane];
                f16x8 bl = Bl[((size_t)(nt0 + t) * 8 + ks) * 64 + lane];
                acch[t] = __builtin_amdgcn_mfma_f32_16x16x32_f16(a0, bh, acch[t], 0, 0, 0);
                accl[t] = __builtin_amdgcn_mfma_f32_16x16x32_f16(a0, bl, accl[t], 0, 0, 0);
            }
        }
        float p[4] = {0.f, 0.f, 0.f, 0.f};
        #pragma unroll
        for (int t = 0; t < 4; t++) {
            float bn = a.b2[(nt0 + t) * 16 + lm];
            #pragma unroll
            for (int r = 0; r < 4; r++)
                p[r] += gelu_exact(acch[t][r] + accl[t][r] * (1.0f / 4096.0f) + bn);
        }
        #pragma unroll
        for (int off = 1; off < 16; off <<= 1)
            #pragma unroll
            for (int r = 0; r < 4; r++)
                p[r] += __shfl_xor(p[r], off, 64);
        if (lm == 0)
            #pragma unroll
            for (int r = 0; r < 4; r++)
                part[wave][quad * 4 + r] = p[r];
        __syncthreads();
        if (tid < 16) {
            float s = part[0][tid] + part[1][tid] + part[2][tid] + part[3][tid];
            a.out[mt * 16 + tid] = s * (1.0f / 256.0f);
        }
        __syncthreads();
    }
}

// ===========================================================================
// Fallback path: R8's verified 4-dispatch pipeline (identical math).
// ===========================================================================
__global__ __launch_bounds__(256) void prep(const float* __restrict__ x,
                                            const int* __restrict__ ei,
                                            const float* __restrict__ We,
                                            const float* __restrict__ be,
                                            const float* __restrict__ W1,
                                            const float* __restrict__ b1,
                                            const float* __restrict__ W2,
                                            u16* __restrict__ xh, u16* __restrict__ xl,
                                            int* __restrict__ cnt, int* __restrict__ bins,
                                            _Float16* __restrict__ w2h, _Float16* __restrict__ w2l,
                                            u16* __restrict__ wch, u16* __restrict__ wcl,
                                            float* __restrict__ bc) {
    const int b = blockIdx.x, tid = threadIdx.x;
    if (b < 1250) {
        __shared__ float xs[16][132];
        {
            int r = tid >> 4, ci = tid & 15;
            const float* xrow = x + (size_t)(b * 16 + r) * FEAT;
            #pragma unroll
            for (int it = 0; it < 8; it++) {
                int col = ci + it * 16;
                xs[r][col] = (col < FEAT) ? xrow[col] : 0.0f;
            }
        }
        __syncthreads();
        int lane = tid & 63, ks = tid >> 6;
        int row = lane & 15, k0 = ks * 32 + (lane >> 4) * 8;
        Frag hi, lo;
        #pragma unroll
        for (int j = 0; j < 8; j++) {
            float v = xs[row][k0 + j];
            u16 h = f2bf(v);
            hi.u[j] = h; lo.u[j] = f2bf(v - bf2f(h));
        }
        size_t fid = (size_t)b * 256 + tid;
        ((s16x8*)xh)[fid] = hi.v;
        ((s16x8*)xl)[fid] = lo.v;
    } else if (b < 2500) {
        int e = (b - 1250) * 256 + tid;
        int s = ei[e];
        int d = ei[N_EDGES + e];
        int p = atomicAdd(&cnt[d], 1);
        if (p < CAP) bins[(size_t)d * CAP + p] = s;
    } else if (b < 2532) {
        int fid = (b - 2500) * 256 + tid;
        int lane = fid & 63, ks = (fid >> 6) & 7, nt = fid >> 9;
        int n = nt * 16 + (lane & 15);
        int k0 = ks * 32 + (lane >> 4) * 8;
        FragH hi, lo;
        #pragma unroll
        for (int j = 0; j < 8; j++) {
            float v = W2[(size_t)(k0 + j) * 256 + n];
            _Float16 h = (_Float16)v;
            hi.h[j] = h;
            lo.h[j] = (_Float16)((v - (float)h) * 4096.0f);
        }
        ((f16x8*)w2h)[fid] = hi.v;
        ((f16x8*)w2l)[fid] = lo.v;
    } else {
        int f = b - 2532;
        int n = tid;
        if (f < 128) {
            float acc = 0.0f;
            if (f < FEAT) {
                const float* wr = We + (size_t)f * 256;
                #pragma unroll 8
                for (int c = 0; c < 256; c++) acc += wr[c] * W1[(size_t)c * 256 + n];
            }
            int nt = n >> 4, lm = n & 15, ks = f >> 5, q = (f >> 3) & 3, j = f & 7;
            size_t idx = (((size_t)nt * 4 + ks) * 64 + q * 16 + lm) * 8 + j;
            u16 h = f2bf(acc);
            wch[idx] = h;
            wcl[idx] = f2bf(acc - bf2f(h));
        } else {
            float acc = b1[n];
            #pragma unroll 8
            for (int c = 0; c < 256; c++) acc += be[c] * W1[(size_t)c * 256 + n];
            bc[n] = acc;
        }
    }
}

__global__ __launch_bounds__(256) void gemm_main_k(const u16* __restrict__ Ah_, const u16* __restrict__ Al_,
                                                   const u16* __restrict__ Bh_, const u16* __restrict__ Bl_,
                                                   const float* __restrict__ bias,
                                                   _Float16* __restrict__ Mout) {
    __shared__ _Float16 Ls[16][256];
    const int tid = threadIdx.x, wave = tid >> 6, lane = tid & 63;
    const int quad = lane >> 4, lm = lane & 15;
    const int mt = blockIdx.x, nt0 = wave * 4;
    const s16x8* Ah = (const s16x8*)Ah_; const s16x8* Al = (const s16x8*)Al_;
    const s16x8* Bh = (const s16x8*)Bh_; const s16x8* Bl = (const s16x8*)Bl_;
    f32x4 acc[4] = {f32x4{0,0,0,0}, f32x4{0,0,0,0}, f32x4{0,0,0,0}, f32x4{0,0,0,0}};
    #pragma unroll
    for (int ks = 0; ks < 4; ks++) {
        s16x8 a_h = Ah[((size_t)mt * 4 + ks) * 64 + lane];
        s16x8 a_l = Al[((size_t)mt * 4 + ks) * 64 + lane];
        #pragma unroll
        for (int t = 0; t < 4; t++) {
            s16x8 bh = Bh[((size_t)(nt0 + t) * 4 + ks) * 64 + lane];
            s16x8 bl = Bl[((size_t)(nt0 + t) * 4 + ks) * 64 + lane];
            acc[t] = __builtin_amdgcn_mfma_f32_16x16x32_bf16(a_h, bh, acc[t], 0, 0, 0);
            acc[t] = __builtin_amdgcn_mfma_f32_16x16x32_bf16(a_l, bh, acc[t], 0, 0, 0);
            acc[t] = __builtin_amdgcn_mfma_f32_16x16x32_bf16(a_h, bl, acc[t], 0, 0, 0);
        }
    }
    #pragma unroll
    for (int t = 0; t < 4; t++) {
        float bn = bias[(nt0 + t) * 16 + lm];
        #pragma unroll
        for (int r = 0; r < 4; r++)
            Ls[quad * 4 + r][(nt0 + t) * 16 + lm] = (_Float16)gelu_exact(acc[t][r] + bn);
    }
    __syncthreads();
    s16x8* dst = (s16x8*)Mout + (size_t)mt * 512;
    const s16x8* src = (const s16x8*)&Ls[0][0];
    dst[tid]       = src[tid];
    dst[256 + tid] = src[256 + tid];
}

__global__ __launch_bounds__(256) void aggregate_k(const _Float16* __restrict__ M,
                                                   const int* __restrict__ cnt,
                                                   const int* __restrict__ bins,
                                                   _Float16* __restrict__ aggf) {
    int node = (blockIdx.x * 256 + threadIdx.x) >> 6;
    int lane = threadIdx.x & 63;
    int c = cnt[node];
    int cc = min(c, CAP);
    int myid = (lane < CAP) ? bins[(size_t)node * CAP + lane] : 0;
    float a0 = 0.f, a1 = 0.f, a2 = 0.f, a3 = 0.f;
    for (int j = 0; j < cc; j += 8) {
        f16x4 v[8];
        #pragma unroll
        for (int u = 0; u < 8; u++) {
            int s = __shfl(myid, min(j + u, cc - 1), 64);
            v[u] = *(const f16x4*)(M + (size_t)s * CH + lane * 4);
        }
        #pragma unroll
        for (int u = 0; u < 8; u++) {
            if (j + u < cc) {
                a0 += (float)v[u].x; a1 += (float)v[u].y;
                a2 += (float)v[u].z; a3 += (float)v[u].w;
            }
        }
    }
    float inv = 1.0f / (float)max(c, 1);
    f16x4 o;
    o.x = (_Float16)(a0 * inv); o.y = (_Float16)(a1 * inv);
    o.z = (_Float16)(a2 * inv); o.w = (_Float16)(a3 * inv);
    int mt = node >> 4, lm = node & 15;
    int ks = lane >> 3, quad = (lane & 7) >> 1, j0 = (lane & 1) * 4;
    size_t base = (((size_t)mt * 8 + ks) * 64 + quad * 16 + lm) * 8 + j0;
    *(f16x4*)(aggf + base) = o;
}

__global__ __launch_bounds__(256) void gemm_mean_k(const _Float16* __restrict__ Af_,
                                                   const _Float16* __restrict__ Bh_, const _Float16* __restrict__ Bl_,
                                                   const float* __restrict__ bias,
                                                   float* __restrict__ out) {
    __shared__ float part[4][32];
    const int tid = threadIdx.x, wave = tid >> 6, lane = tid & 63;
    const int quad = lane >> 4, lm = lane & 15;
    const int mt0 = blockIdx.x * 2, nt0 = wave * 4;
    const f16x8* Af = (const f16x8*)Af_;
    const f16x8* Bh = (const f16x8*)Bh_; const f16x8* Bl = (const f16x8*)Bl_;
    f32x4 acch[2][4], accl[2][4];
    #pragma unroll
    for (int mi = 0; mi < 2; mi++)
        #pragma unroll
        for (int t = 0; t < 4; t++) {
            acch[mi][t] = f32x4{0.f, 0.f, 0.f, 0.f};
            accl[mi][t] = f32x4{0.f, 0.f, 0.f, 0.f};
        }
    #pragma unroll
    for (int ks = 0; ks < 8; ks++) {
        f16x8 a0 = Af[((size_t)(mt0 + 0) * 8 + ks) * 64 + lane];
        f16x8 a1 = Af[((size_t)(mt0 + 1) * 8 + ks) * 64 + lane];
        #pragma unroll
        for (int t = 0; t < 4; t++) {
            f16x8 bh = Bh[((size_t)(nt0 + t) * 8 + ks) * 64 + lane];
            f16x8 bl = Bl[((size_t)(nt0 + t) * 8 + ks) * 64 + lane];
            acch[0][t] = __builtin_amdgcn_mfma_f32_16x16x32_f16(a0, bh, acch[0][t], 0, 0, 0);
            accl[0][t] = __builtin_amdgcn_mfma_f32_16x16x32_f16(a0, bl, accl[0][t], 0, 0, 0);
            acch[1][t] = __builtin_amdgcn_mfma_f32_16x16x32_f16(a1, bh, acch[1][t], 0, 0, 0);
            accl[1][t] = __builtin_amdgcn_mfma_f32_16x16x32_f16(a1, bl, accl[1][t], 0, 0, 0);
        }
    }
    float p[2][4] = {{0.f,0.f,0.f,0.f},{0.f,0.f,0.f,0.f}};
    #pragma unroll
    for (int t = 0; t < 4; t++) {
        float bn = bias[(nt0 + t) * 16 + lm];
        #pragma unroll
        for (int mi = 0; mi < 2; mi++)
            #pragma unroll
            for (int r = 0; r < 4; r++)
                p[mi][r] += gelu_exact(acch[mi][t][r] + accl[mi][t][r] * (1.0f / 4096.0f) + bn);
    }
    #pragma unroll
    for (int off = 1; off < 16; off <<= 1)
        #pragma unroll
        for (int mi = 0; mi < 2; mi++)
            #pragma unroll
            for (int r = 0; r < 4; r++)
                p[mi][r] += __shfl_xor(p[mi][r], off, 64);
    if (lm == 0)
        #pragma unroll
        for (int mi = 0; mi < 2; mi++)
            #pragma unroll
            for (int r = 0; r < 4; r++)
                part[wave][mi * 16 + quad * 4 + r] = p[mi][r];
    __syncthreads();
    if (tid < 32) {
        float s = part[0][tid] + part[1][tid] + part[2][tid] + part[3][tid];
        out[blockIdx.x * 32 + tid] = s * (1.0f / 256.0f);
    }
}

extern "C" void kernel_launch(void* const* d_in, const int* in_sizes, int n_in,
                              void* d_out, int out_size, void* d_ws, size_t ws_size,
                              hipStream_t stream) {
    char* ws = (char*)d_ws;
    size_t off = 0;
    u16* xh = (u16*)(ws + off);                           // 5,120,000 (dead after gemm_main)
    _Float16* aggf = (_Float16*)(ws + off);               // 10,240,000 (overlaps xh/xl)
    off += 5120000;
    u16* xl = (u16*)(ws + off); off += 5120000;
    _Float16* M = (_Float16*)(ws + off); off += 10240000; // 20000*256 fp16
    u16* wch = (u16*)(ws + off); off += 65536;            // Wc bf16 hi B-frags (K=128)
    u16* wcl = (u16*)(ws + off); off += 65536;
    _Float16* w2h = (_Float16*)(ws + off); off += 131072; // W2 fp16 wh B-frags (K=256)
    _Float16* w2l = (_Float16*)(ws + off); off += 131072; // W2 fp16 wl*4096
    float* bc = (float*)(ws + off); off += 1024;
    int* cnt  = (int*)(ws + off); off += N_NODES * 4;
    int* bins = (int*)(ws + off); off += (size_t)N_NODES * CAP * 4;

    MegaArgs ma;
    ma.x  = (const float*)d_in[0];
    ma.ei = (const int*)d_in[1];
    ma.We = (const float*)d_in[2];
    ma.be = (const float*)d_in[3];
    ma.W1 = (const float*)d_in[4];
    ma.b1 = (const float*)d_in[5];
    ma.W2 = (const float*)d_in[6];
    ma.b2 = (const float*)d_in[7];
    ma.xh = xh; ma.xl = xl; ma.cnt = cnt; ma.bins = bins;
    ma.w2h = w2h; ma.w2l = w2l; ma.wch = wch; ma.wcl = wcl;
    ma.bc = bc; ma.M = M; ma.aggf = aggf;
    ma.out = (float*)d_out;

    void* kp[] = { &ma };
    hipError_t err = hipLaunchCooperativeKernel((void*)mega, dim3(GRID), dim3(256),
                                                kp, 0, stream);
    if (err != hipSuccess) {
        (void)hipGetLastError();   // clear sticky error, take the 4-dispatch path
        (void)hipMemsetAsync(cnt, 0, N_NODES * sizeof(int), stream);
        prep<<<2661, 256, 0, stream>>>(ma.x, ma.ei, ma.We, ma.be, ma.W1, ma.b1, ma.W2,
                                       xh, xl, cnt, bins, w2h, w2l, wch, wcl, bc);
        gemm_main_k<<<N_NODES / 16, 256, 0, stream>>>(xh, xl, wch, wcl, bc, M);
        aggregate_k<<<N_NODES / 4, 256, 0, stream>>>(M, cnt, bins, aggf);
        gemm_mean_k<<<N_NODES / 32, 256, 0, stream>>>(aggf, w2h, w2l, ma.b2, (float*)d_out);
    }
}

// Round 12
// 153.331 us; speedup vs baseline: 3.4617x; 3.4617x over previous
//
#include <hip/hip_runtime.h>
#include <math.h>

#define N_NODES 20000
#define N_EDGES 320000
#define CH      256
#define FEAT    118
#define CAP     48   // in-degree cap; dst ~ Poisson(16), P(any>48) ~ 2e-7

typedef float    f32x4 __attribute__((ext_vector_type(4)));
typedef short    s16x8 __attribute__((ext_vector_type(8)));
typedef _Float16 f16x4 __attribute__((ext_vector_type(4)));
typedef _Float16 f16x8 __attribute__((ext_vector_type(8)));
typedef unsigned short u16;

union Frag  { s16x8 v; u16 u[8]; };
union FragH { f16x8 v; _Float16 h[8]; };

__device__ __forceinline__ float gelu_exact(float x) {
    return 0.5f * x * (1.0f + erff(x * 0.70710678118654752f));
}
__device__ __forceinline__ u16 f2bf(float f) {
    unsigned u = __float_as_uint(f);
    u = (u + 0x7FFFu + ((u >> 16) & 1u)) >> 16;
    return (u16)u;
}
__device__ __forceinline__ float bf2f(u16 h) { return __uint_as_float(((unsigned)h) << 16); }

// ---------------------------------------------------------------------------
// Dispatch 1 -- prep: pack_x | pack W2 | compose Wc=We@W1, bc | zero cnt
//   A-frag [mt][ks][lane][8]: elem j = A[mt*16+(lane&15)][ks*32+(lane>>4)*8+j]
//   B-frag [nt][ks][lane][8]: elem j = B[ks*32+(lane>>4)*8+j][nt*16+(lane&15)]
// grid = 1250 + 32 + 129 + 79 = 1490 blocks
// ---------------------------------------------------------------------------
__global__ __launch_bounds__(256) void prep(const float* __restrict__ x,
                                            const float* __restrict__ We,
                                            const float* __restrict__ be,
                                            const float* __restrict__ W1,
                                            const float* __restrict__ b1,
                                            const float* __restrict__ W2,
                                            u16* __restrict__ xh, u16* __restrict__ xl,
                                            int* __restrict__ cnt,
                                            _Float16* __restrict__ w2h, _Float16* __restrict__ w2l,
                                            u16* __restrict__ wch, u16* __restrict__ wcl,
                                            float* __restrict__ bc) {
    const int b = blockIdx.x, tid = threadIdx.x;
    if (b < 1250) {                       // ---- pack_x: one 16-row m-tile (LDS bounce)
        __shared__ float xs[16][132];     // pitch 132: 16B-aligned rows, bank stride 4
        {
            int r = tid >> 4, ci = tid & 15;
            const float* xrow = x + (size_t)(b * 16 + r) * FEAT;
            #pragma unroll
            for (int it = 0; it < 8; it++) {
                int col = ci + it * 16;
                xs[r][col] = (col < FEAT) ? xrow[col] : 0.0f;
            }
        }
        __syncthreads();
        int lane = tid & 63, ks = tid >> 6;
        int row = lane & 15, k0 = ks * 32 + (lane >> 4) * 8;
        Frag hi, lo;
        #pragma unroll
        for (int j = 0; j < 8; j++) {
            float v = xs[row][k0 + j];
            u16 h = f2bf(v);
            hi.u[j] = h; lo.u[j] = f2bf(v - bf2f(h));
        }
        size_t fid = (size_t)b * 256 + tid;   // == ((b*4+ks)*64+lane)
        ((s16x8*)xh)[fid] = hi.v;
        ((s16x8*)xl)[fid] = lo.v;
    } else if (b < 1282) {                // ---- pack W2 -> fp16 wh + 4096*wl B-frags, KS=8
        int fid = (b - 1250) * 256 + tid;
        int lane = fid & 63, ks = (fid >> 6) & 7, nt = fid >> 9;
        int n = nt * 16 + (lane & 15);
        int k0 = ks * 32 + (lane >> 4) * 8;
        FragH hi, lo;
        #pragma unroll
        for (int j = 0; j < 8; j++) {
            float v = W2[(size_t)(k0 + j) * 256 + n];
            _Float16 h = (_Float16)v;
            hi.h[j] = h;
            lo.h[j] = (_Float16)((v - (float)h) * 4096.0f);   // keep wl normal-range
        }
        ((f16x8*)w2h)[fid] = hi.v;
        ((f16x8*)w2l)[fid] = lo.v;
    } else if (b < 1411) {                // ---- compose: Wc row f (f<128) or bc (f==128)
        int f = b - 1282;
        int n = tid;
        if (f < 128) {
            float acc = 0.0f;
            if (f < FEAT) {
                const float* wr = We + (size_t)f * 256;
                #pragma unroll 8
                for (int c = 0; c < 256; c++) acc += wr[c] * W1[(size_t)c * 256 + n];
            }
            int nt = n >> 4, lm = n & 15, ks = f >> 5, q = (f >> 3) & 3, j = f & 7;
            size_t idx = (((size_t)nt * 4 + ks) * 64 + q * 16 + lm) * 8 + j;
            u16 h = f2bf(acc);
            wch[idx] = h;
            wcl[idx] = f2bf(acc - bf2f(h));
        } else {
            float acc = b1[n];
            #pragma unroll 8
            for (int c = 0; c < 256; c++) acc += be[c] * W1[(size_t)c * 256 + n];
            bc[n] = acc;
        }
    } else {                              // ---- zero cnt (consumed by next dispatch)
        int g = (b - 1411) * 256 + tid;
        if (g < N_NODES) cnt[g] = 0;
    }
}

// ---------------------------------------------------------------------------
// Dispatch 2 -- main_bins: blocks 0..1249 gemm_main (16-row tiles), blocks
// 1250..2499 fill_bins. Independent work sharing one dispatch.
// gemm_main: M = gelu(x @ Wc + bc), K=128 (KS=4), split-bf16 3-term MFMA.
// ---------------------------------------------------------------------------
__global__ __launch_bounds__(256) void main_bins(const u16* __restrict__ Ah_, const u16* __restrict__ Al_,
                                                 const u16* __restrict__ Bh_, const u16* __restrict__ Bl_,
                                                 const float* __restrict__ bias,
                                                 const int* __restrict__ ei,
                                                 int* __restrict__ cnt, int* __restrict__ bins,
                                                 _Float16* __restrict__ Mout) {
    const int b = blockIdx.x, tid = threadIdx.x;
    if (b >= 1250) {                      // ---- fill_bins
        int e = (b - 1250) * 256 + tid;
        int s = ei[e];
        int d = ei[N_EDGES + e];
        int p = atomicAdd(&cnt[d], 1);
        if (p < CAP) bins[(size_t)d * CAP + p] = s;
        return;
    }
    // ---- gemm_main 16-row m-tile
    __shared__ _Float16 Ls[16][256];
    const int wave = tid >> 6, lane = tid & 63;
    const int quad = lane >> 4, lm = lane & 15;
    const int mt = b, nt0 = wave * 4;
    const s16x8* Ah = (const s16x8*)Ah_; const s16x8* Al = (const s16x8*)Al_;
    const s16x8* Bh = (const s16x8*)Bh_; const s16x8* Bl = (const s16x8*)Bl_;
    f32x4 acc[4] = {f32x4{0,0,0,0}, f32x4{0,0,0,0}, f32x4{0,0,0,0}, f32x4{0,0,0,0}};
    #pragma unroll
    for (int ks = 0; ks < 4; ks++) {
        s16x8 a_h = Ah[((size_t)mt * 4 + ks) * 64 + lane];
        s16x8 a_l = Al[((size_t)mt * 4 + ks) * 64 + lane];
        #pragma unroll
        for (int t = 0; t < 4; t++) {
            s16x8 bh = Bh[((size_t)(nt0 + t) * 4 + ks) * 64 + lane];
            s16x8 bl = Bl[((size_t)(nt0 + t) * 4 + ks) * 64 + lane];
            acc[t] = __builtin_amdgcn_mfma_f32_16x16x32_bf16(a_h, bh, acc[t], 0, 0, 0);
            acc[t] = __builtin_amdgcn_mfma_f32_16x16x32_bf16(a_l, bh, acc[t], 0, 0, 0);
            acc[t] = __builtin_amdgcn_mfma_f32_16x16x32_bf16(a_h, bl, acc[t], 0, 0, 0);
        }
    }
    #pragma unroll
    for (int t = 0; t < 4; t++) {
        float bn = bias[(nt0 + t) * 16 + lm];
        #pragma unroll
        for (int r = 0; r < 4; r++)
            Ls[quad * 4 + r][(nt0 + t) * 16 + lm] = (_Float16)gelu_exact(acc[t][r] + bn);
    }
    __syncthreads();
    s16x8* dst = (s16x8*)Mout + (size_t)mt * 512;   // 16 rows * 32 frags
    const s16x8* src = (const s16x8*)&Ls[0][0];
    dst[tid]       = src[tid];
    dst[256 + tid] = src[256 + tid];
}

// ---------------------------------------------------------------------------
// Dispatch 3 -- aggregate: one wave per node, 8-deep batched gathers (min-
// clamp tail duplicates hit the same row -> L1). Output in packed-A fp16
// fragment layout (KS=8) for gemm_mean.
// ---------------------------------------------------------------------------
__global__ __launch_bounds__(256) void aggregate(const _Float16* __restrict__ M,
                                                 const int* __restrict__ cnt,
                                                 const int* __restrict__ bins,
                                                 _Float16* __restrict__ aggf) {
    int node = (blockIdx.x * 256 + threadIdx.x) >> 6;
    int lane = threadIdx.x & 63;
    int c = cnt[node];
    int cc = min(c, CAP);
    int myid = (lane < CAP) ? bins[(size_t)node * CAP + lane] : 0;
    float a0 = 0.f, a1 = 0.f, a2 = 0.f, a3 = 0.f;
    for (int j = 0; j < cc; j += 8) {
        f16x4 v[8];
        #pragma unroll
        for (int u = 0; u < 8; u++) {
            int s = __shfl(myid, min(j + u, cc - 1), 64);
            v[u] = *(const f16x4*)(M + (size_t)s * CH + lane * 4);
        }
        #pragma unroll
        for (int u = 0; u < 8; u++) {
            if (j + u < cc) {   // wave-uniform predicate
                a0 += (float)v[u].x; a1 += (float)v[u].y;
                a2 += (float)v[u].z; a3 += (float)v[u].w;
            }
        }
    }
    float inv = 1.0f / (float)max(c, 1);
    f16x4 o;
    o.x = (_Float16)(a0 * inv); o.y = (_Float16)(a1 * inv);
    o.z = (_Float16)(a2 * inv); o.w = (_Float16)(a3 * inv);
    // ch = lane*4+q -> packed-A (KS=8): ks=lane>>3, quad=(lane&7)>>1, j0=(lane&1)*4
    int mt = node >> 4, lm = node & 15;
    int ks = lane >> 3, quad = (lane & 7) >> 1, j0 = (lane & 1) * 4;
    size_t base = (((size_t)mt * 8 + ks) * 64 + quad * 16 + lm) * 8 + j0;
    *(f16x4*)(aggf + base) = o;
}

// ---------------------------------------------------------------------------
// Dispatch 4 -- gemm_mean (16-row blocks, 1250 for TLP; logic verified in R11
// mega P4): out = mean_ch gelu(agg @ W2 + b2). A = exact fp16 packed frags
// (1 term); B = fp16 wh + 4096-scaled wl (2 acc sets, combined in epilogue).
// ---------------------------------------------------------------------------
__global__ __launch_bounds__(256) void gemm_mean(const _Float16* __restrict__ Af_,
                                                 const _Float16* __restrict__ Bh_, const _Float16* __restrict__ Bl_,
                                                 const float* __restrict__ bias,
                                                 float* __restrict__ out) {
    __shared__ float part[4][16];
    const int tid = threadIdx.x, wave = tid >> 6, lane = tid & 63;
    const int quad = lane >> 4, lm = lane & 15;
    const int mt = blockIdx.x, nt0 = wave * 4;
    const f16x8* Af = (const f16x8*)Af_;
    const f16x8* Bh = (const f16x8*)Bh_; const f16x8* Bl = (const f16x8*)Bl_;
    f32x4 acch[4], accl[4];
    #pragma unroll
    for (int t = 0; t < 4; t++) {
        acch[t] = f32x4{0.f, 0.f, 0.f, 0.f};
        accl[t] = f32x4{0.f, 0.f, 0.f, 0.f};
    }
    #pragma unroll
    for (int ks = 0; ks < 8; ks++) {
        f16x8 a0 = Af[((size_t)mt * 8 + ks) * 64 + lane];
        #pragma unroll
        for (int t = 0; t < 4; t++) {
            f16x8 bh = Bh[((size_t)(nt0 + t) * 8 + ks) * 64 + lane];
            f16x8 bl = Bl[((size_t)(nt0 + t) * 8 + ks) * 64 + lane];
            acch[t] = __builtin_amdgcn_mfma_f32_16x16x32_f16(a0, bh, acch[t], 0, 0, 0);
            accl[t] = __builtin_amdgcn_mfma_f32_16x16x32_f16(a0, bl, accl[t], 0, 0, 0);
        }
    }
    float p[4] = {0.f, 0.f, 0.f, 0.f};
    #pragma unroll
    for (int t = 0; t < 4; t++) {
        float bn = bias[(nt0 + t) * 16 + lm];
        #pragma unroll
        for (int r = 0; r < 4; r++)
            p[r] += gelu_exact(acch[t][r] + accl[t][r] * (1.0f / 4096.0f) + bn);
    }
    #pragma unroll
    for (int off = 1; off < 16; off <<= 1)
        #pragma unroll
        for (int r = 0; r < 4; r++)
            p[r] += __shfl_xor(p[r], off, 64);
    if (lm == 0)
        #pragma unroll
        for (int r = 0; r < 4; r++)
            part[wave][quad * 4 + r] = p[r];
    __syncthreads();
    if (tid < 16) {
        float s = part[0][tid] + part[1][tid] + part[2][tid] + part[3][tid];
        out[mt * 16 + tid] = s * (1.0f / 256.0f);
    }
}

extern "C" void kernel_launch(void* const* d_in, const int* in_sizes, int n_in,
                              void* d_out, int out_size, void* d_ws, size_t ws_size,
                              hipStream_t stream) {
    const float* x  = (const float*)d_in[0];
    const int*   ei = (const int*)d_in[1];
    const float* We = (const float*)d_in[2];
    const float* be = (const float*)d_in[3];
    const float* W1 = (const float*)d_in[4];
    const float* b1 = (const float*)d_in[5];
    const float* W2 = (const float*)d_in[6];
    const float* b2 = (const float*)d_in[7];
    float* out = (float*)d_out;

    // ws layout: xh/xl (10.24 MB) dead after main_bins -> reused as aggf (fp16).
    char* ws = (char*)d_ws;
    size_t off = 0;
    u16* xh = (u16*)(ws + off);                           // 5,120,000
    _Float16* aggf = (_Float16*)(ws + off);               // 10,240,000 (overlaps xh/xl)
    off += 5120000;
    u16* xl = (u16*)(ws + off); off += 5120000;
    _Float16* M = (_Float16*)(ws + off); off += 10240000; // 20000*256 fp16
    u16* wch = (u16*)(ws + off); off += 65536;            // Wc bf16 hi B-frags (K=128)
    u16* wcl = (u16*)(ws + off); off += 65536;
    _Float16* w2h = (_Float16*)(ws + off); off += 131072; // W2 fp16 wh B-frags (K=256)
    _Float16* w2l = (_Float16*)(ws + off); off += 131072; // W2 fp16 wl*4096
    float* bc = (float*)(ws + off); off += 1024;
    int* cnt  = (int*)(ws + off); off += N_NODES * 4;
    int* bins = (int*)(ws + off); off += (size_t)N_NODES * CAP * 4;

    prep<<<1490, 256, 0, stream>>>(x, We, be, W1, b1, W2,
                                   xh, xl, cnt, w2h, w2l, wch, wcl, bc);
    main_bins<<<2500, 256, 0, stream>>>(xh, xl, wch, wcl, bc, ei, cnt, bins, M);
    aggregate<<<N_NODES / 4, 256, 0, stream>>>(M, cnt, bins, aggf);
    gemm_mean<<<1250, 256, 0, stream>>>(aggf, w2h, w2l, b2, out);
}